// Round 3
// baseline (206.737 us; speedup 1.0000x reference)
//
#include <hip/hip_runtime.h>
#include <math.h>

namespace {
constexpr int HOP_    = 256;
constexpr int FRAMES_ = 1024;
constexpr int BATCH_  = 16;
constexpr int BINS_   = 513;
constexpr int OUTLEN_ = 262912;               // (1024-1)*256 + 1024
constexpr int FPB_    = 8;                    // frames owned per block
constexpr int BPB_    = FRAMES_ / FPB_;       // 128 blocks per batch
constexpr int OWN_    = FPB_ * HOP_;          // 2048 owned samples
constexpr int BUF_    = OWN_ + 768;           // 2816 (last block)
constexpr int SKEW_   = BUF_ + (BUF_ >> 5);   // 2904 skewed floats (11.6 KB)
}

__device__ __forceinline__ void cmul(float& xr, float& xi, float yr, float yi) {
    float tr = xr * yr - xi * yi;
    xi = xr * yi + xi * yr;
    xr = tr;
}

// One wave = one frame FFT, entirely in registers + __shfl_xor.
// Block of 4 waves owns output span [F0*HOP, F0*HOP+blen); frames F0-3..F0+7
// are distributed over the waves; accumulation via LDS float atomics into a
// skewed accumulator (A(s)=s+(s>>5): 16-aligned chunks -> 2-way banks, free).
__global__ __launch_bounds__(256, 4)
void istft_reg_kernel(const float* __restrict__ sre,
                      const float* __restrict__ sim,
                      float* __restrict__ out)
{
    __shared__ float acc[SKEW_];
    const int tid   = threadIdx.x;
    const int l     = tid & 63;
    const int wv    = tid >> 6;
    const int blkid = blockIdx.x;
    const int b     = blockIdx.y;
    const int F0    = blkid * FPB_;
    const int blen  = (blkid == BPB_ - 1) ? BUF_ : OWN_;

    for (int u = tid; u < SKEW_; u += 256) acc[u] = 0.0f;

    // ---- per-lane constants (computed once, reused for all frames) ----
    // Wk[r] = e^{2pi i (l+64r)/1024}  (r2c packing twiddle)
    float Wkr[8], Wki[8];
    {
        float s, c; sincosf(0.006135923151542565f * (float)l, &s, &c);
        Wkr[0] = c; Wki[0] = s;
        const float pr = 0.9238795325112867f, pq = 0.3826834323650898f; // e^{2pi i/16}
        #pragma unroll
        for (int r = 1; r < 8; ++r) {
            Wkr[r] = Wkr[r-1]; Wki[r] = Wki[r-1];
            cmul(Wkr[r], Wki[r], pr, pq);
        }
    }
    // TW[m1] = (omega512^l)^{m1}  (four-step twiddle); omega512^l = Wk[0]^2
    float TWr[8], TWi[8];
    {
        TWr[0] = 1.f; TWi[0] = 0.f;
        float tr = Wkr[0], ti = Wki[0];
        cmul(tr, ti, Wkr[0], Wki[0]);
        TWr[1] = tr; TWi[1] = ti;
        #pragma unroll
        for (int m = 2; m < 8; ++m) {
            TWr[m] = TWr[m-1]; TWi[m] = TWi[m-1];
            cmul(TWr[m], TWi[m], tr, ti);
        }
    }
    // stage twiddles for 64-pt cross-lane DIF: TS[s] = e^{2pi i (l&(H-1))/(2H)}, H=32>>s
    float TSr[6], TSi[6];
    #pragma unroll
    for (int s = 0; s < 6; ++s) {
        const int H = 32 >> s;
        const float ang = 0.09817477042468103f * (float)((l & (H - 1)) << s); // pi/32 * .
        float ss, cc; sincosf(ang, &ss, &cc);
        TSr[s] = cc; TSi[s] = ss;
    }
    // bit-reversed chunk base + 16 hann window values (lane-constant)
    const int B = ((l & 1) << 5) | ((l & 2) << 3) | ((l & 4) << 1) |
                  ((l & 8) >> 1) | ((l & 16) >> 3) | ((l & 32) >> 5);
    const int n0 = B << 4;
    float wnd[16];
    {
        float s, c; sincosf(0.006135923151542565f * (float)n0, &s, &c);
        const float C1 = 0.9999811752826011f, S1 = 0.006135884649154475f;
        #pragma unroll
        for (int j = 0; j < 16; ++j) {
            wnd[j] = 0.5f - 0.5f * c;
            cmul(c, s, C1, S1);
        }
    }

    __syncthreads();   // acc zeroing visible to all waves

    const float cs = 1.0f / 1024.0f;

    for (int fi = wv - 3; fi < FPB_; fi += 4) {
        const int f = F0 + fi;
        if (f < 0) continue;                    // wave-uniform
        const size_t base = ((size_t)b * FRAMES_ + f) * BINS_;

        // ---- z-prep: Z[k]=E+iO, k=l+64r (scale 1/1024 folds 1/2 and 1/512)
        float Yr[8], Yi[8];
        #pragma unroll
        for (int r = 0; r < 8; ++r) {
            const int k = l + 64 * r;
            float ar = sre[base + k];
            float ai = sim[base + k];
            float br = sre[base + 512 - k];
            float bi = -sim[base + 512 - k];
            if (r == 0 && l == 0) { ai = 0.f; bi = 0.f; }  // c2r: bins 0,512 imag ignored
            const float er = (ar + br) * cs, ei = (ai + bi) * cs;
            const float dr = (ar - br) * cs, di = (ai - bi) * cs;
            const float orr = Wkr[r] * dr - Wki[r] * di;
            const float oii = Wkr[r] * di + Wki[r] * dr;
            Yr[r] = er - oii;
            Yi[r] = ei + orr;
        }

        // ---- in-lane 8-pt DFT (sign +) over r -> slot m1
        {
            const float t0r = Yr[0] + Yr[4], t0i = Yi[0] + Yi[4];
            const float t1r = Yr[0] - Yr[4], t1i = Yi[0] - Yi[4];
            const float t2r = Yr[2] + Yr[6], t2i = Yi[2] + Yi[6];
            const float t3r = Yr[2] - Yr[6], t3i = Yi[2] - Yi[6];
            const float E0r = t0r + t2r, E0i = t0i + t2i;
            const float E1r = t1r - t3i, E1i = t1i + t3r;
            const float E2r = t0r - t2r, E2i = t0i - t2i;
            const float E3r = t1r + t3i, E3i = t1i - t3r;
            const float u0r = Yr[1] + Yr[5], u0i = Yi[1] + Yi[5];
            const float u1r = Yr[1] - Yr[5], u1i = Yi[1] - Yi[5];
            const float u2r = Yr[3] + Yr[7], u2i = Yi[3] + Yi[7];
            const float u3r = Yr[3] - Yr[7], u3i = Yi[3] - Yi[7];
            const float O0r = u0r + u2r, O0i = u0i + u2i;
            const float O1r = u1r - u3i, O1i = u1i + u3r;
            const float O2r = u0r - u2r, O2i = u0i - u2i;
            const float O3r = u1r + u3i, O3i = u1i - u3r;
            const float rc = 0.7071067811865476f;            // w8 = rc*(1+i)
            const float W1r = rc * (O1r - O1i), W1i = rc * (O1r + O1i);
            const float W2r = -O2i,             W2i = O2r;
            const float W3r = -rc * (O3r + O3i), W3i = rc * (O3r - O3i);
            Yr[0] = E0r + O0r; Yi[0] = E0i + O0i;
            Yr[4] = E0r - O0r; Yi[4] = E0i - O0i;
            Yr[1] = E1r + W1r; Yi[1] = E1i + W1i;
            Yr[5] = E1r - W1r; Yi[5] = E1i - W1i;
            Yr[2] = E2r + W2r; Yi[2] = E2i + W2i;
            Yr[6] = E2r - W2r; Yi[6] = E2i - W2i;
            Yr[3] = E3r + W3r; Yi[3] = E3i + W3i;
            Yr[7] = E3r - W3r; Yi[7] = E3i - W3i;
        }

        // ---- four-step twiddle
        #pragma unroll
        for (int m = 1; m < 8; ++m) cmul(Yr[m], Yi[m], TWr[m], TWi[m]);

        // ---- 64-pt cross-lane DIF, 6 shuffle stages (no LDS, no barriers)
        #pragma unroll
        for (int s = 0; s < 6; ++s) {
            const int H = 32 >> s;
            const bool hi = (l & H) != 0;
            const float tr = TSr[s], ti = TSi[s];
            #pragma unroll
            for (int m = 0; m < 8; ++m) {
                const float orr = __shfl_xor(Yr[m], H, 64);
                const float oii = __shfl_xor(Yi[m], H, 64);
                const float sr = Yr[m] + orr, si = Yi[m] + oii;
                const float dr = orr - Yr[m], di = oii - Yi[m];
                const float wr = dr * tr - di * ti;
                const float wi = dr * ti + di * tr;
                Yr[m] = hi ? wr : sr;
                Yi[m] = hi ? wi : si;
            }
        }
        // lane l, slot m1 holds z[m1 + 8*bitrev6(l)]:
        // time samples 2m -> Re, 2m+1 -> Im; chunk = 16 samples at n0=16*B.

        // ---- window + accumulate (skewed LDS, float atomics)
        const int pos0 = fi * HOP_ + n0;
        if ((unsigned)pos0 < (unsigned)blen) {
            #pragma unroll
            for (int j = 0; j < 16; ++j) {
                const int sidx = pos0 + j;
                const float v = wnd[j] * ((j & 1) ? Yi[j >> 1] : Yr[j >> 1]);
                atomicAdd(&acc[sidx + (sidx >> 5)], v);
            }
        }
    }

    __syncthreads();

    // ---- exclusive write-out of owned span
    const size_t ob = (size_t)b * OUTLEN_ + (size_t)F0 * HOP_;
    for (int s2 = tid; s2 < blen; s2 += 256)
        out[ob + s2] = acc[s2 + (s2 >> 5)];
}

extern "C" void kernel_launch(void* const* d_in, const int* in_sizes, int n_in,
                              void* d_out, int out_size, void* d_ws, size_t ws_size,
                              hipStream_t stream)
{
    (void)in_sizes; (void)n_in; (void)d_ws; (void)ws_size; (void)out_size;
    const float* sre = (const float*)d_in[0];
    const float* sim = (const float*)d_in[1];
    float* out = (float*)d_out;

    istft_reg_kernel<<<dim3(BPB_, BATCH_), dim3(256), 0, stream>>>(sre, sim, out);
}

// Round 8
// 121.493 us; speedup vs baseline: 1.7016x; 1.7016x over previous
//
#include <hip/hip_runtime.h>
#include <math.h>

namespace {
constexpr int HOP_    = 256;
constexpr int FRAMES_ = 1024;
constexpr int BATCH_  = 16;
constexpr int BINS_   = 513;
constexpr int OUTLEN_ = 262912;              // (1024-1)*256 + 1024
constexpr int FPB_    = 16;                  // frames owned per block
constexpr int BPB_    = FRAMES_ / FPB_;      // 64 blocks per batch
constexpr int OWN_    = FPB_ * HOP_;         // 4096 owned samples
constexpr int BUF_    = OWN_ + 768;          // 4864 (last block)
// acc skew S(p) = p + 2*(p>>4); S(4863) = 5469 -> 5472
constexpr int ACCSZ_  = 5472;
// per-wave FFT buffer: 512 + (512>>3) skew -> 576 floats per component
constexpr int FBUF_   = 576;
}

__device__ __forceinline__ void cmul(float& xr, float& xi, float yr, float yi) {
    float tr = xr * yr - xi * yi;
    xi = xr * yi + xi * yr;
    xr = tr;
}

// out[r] = sum_j in[j] * e^{+2pi i r j / 8}   (verified round-3 block)
__device__ __forceinline__ void dft8(float (&Yr)[8], float (&Yi)[8]) {
    const float t0r = Yr[0] + Yr[4], t0i = Yi[0] + Yi[4];
    const float t1r = Yr[0] - Yr[4], t1i = Yi[0] - Yi[4];
    const float t2r = Yr[2] + Yr[6], t2i = Yi[2] + Yi[6];
    const float t3r = Yr[2] - Yr[6], t3i = Yi[2] - Yi[6];
    const float E0r = t0r + t2r, E0i = t0i + t2i;
    const float E1r = t1r - t3i, E1i = t1i + t3r;
    const float E2r = t0r - t2r, E2i = t0i - t2i;
    const float E3r = t1r + t3i, E3i = t1i - t3r;
    const float u0r = Yr[1] + Yr[5], u0i = Yi[1] + Yi[5];
    const float u1r = Yr[1] - Yr[5], u1i = Yi[1] - Yi[5];
    const float u2r = Yr[3] + Yr[7], u2i = Yi[3] + Yi[7];
    const float u3r = Yr[3] - Yr[7], u3i = Yi[3] - Yi[7];
    const float O0r = u0r + u2r, O0i = u0i + u2i;
    const float O1r = u1r - u3i, O1i = u1i + u3r;
    const float O2r = u0r - u2r, O2i = u0i - u2i;
    const float O3r = u1r + u3i, O3i = u1i - u3r;
    const float rc = 0.7071067811865476f;
    const float W1r = rc * (O1r - O1i), W1i = rc * (O1r + O1i);
    const float W2r = -O2i,             W2i = O2r;
    const float W3r = -rc * (O3r + O3i), W3i = rc * (O3r - O3i);
    Yr[0] = E0r + O0r; Yi[0] = E0i + O0i;
    Yr[4] = E0r - O0r; Yi[4] = E0i - O0i;
    Yr[1] = E1r + W1r; Yi[1] = E1i + W1i;
    Yr[5] = E1r - W1r; Yi[5] = E1i - W1i;
    Yr[2] = E2r + W2r; Yi[2] = E2i + W2i;
    Yr[6] = E2r - W2r; Yi[6] = E2i - W2i;
    Yr[3] = E3r + W3r; Yi[3] = E3i + W3i;
    Yr[7] = E3r - W3r; Yi[7] = E3i - W3i;
}

// One wave = one 512-pt radix-8^3 FFT (stage 1 in registers fused with
// z-prep; stages 2,3 via per-wave LDS, no barriers). Block of 4 waves owns
// output span [F0*HOP, F0*HOP+blen); 19 frames (16 owned + 3 halo) are
// processed in 5 steps, concurrent frames spaced 5 apart -> non-atomic
// accumulation with one barrier per step.
__global__ __launch_bounds__(256, 4)
void istft_r8_kernel(const float* __restrict__ sre,
                     const float* __restrict__ sim,
                     float* __restrict__ out)
{
    __shared__ float fftbuf[4 * 2 * FBUF_];   // per wave: Re[576] | Im[576]
    __shared__ __align__(16) float acc[ACCSZ_];

    const int tid   = threadIdx.x;
    const int l     = tid & 63;
    const int wv    = tid >> 6;
    const int blkid = blockIdx.x;
    const int b     = blockIdx.y;
    const int F0    = blkid * FPB_;
    const int blen  = (blkid == BPB_ - 1) ? BUF_ : OWN_;

    float* Re = fftbuf + wv * (2 * FBUF_);
    float* Im = Re + FBUF_;

    for (int u = tid; u < ACCSZ_; u += 256) acc[u] = 0.0f;

    // ---- per-lane constants ----
    // Wk[r] = e^{2pi i (l+64r)/1024}   (r2c packing twiddle)
    float Wkr[8], Wki[8];
    {
        float s, c; sincosf(0.006135923151542565f * (float)l, &s, &c);
        Wkr[0] = c; Wki[0] = s;
        const float pr = 0.9238795325112867f, pq = 0.3826834323650898f; // e^{2pi i/16}
        #pragma unroll
        for (int r = 1; r < 8; ++r) {
            Wkr[r] = Wkr[r-1]; Wki[r] = Wki[r-1];
            cmul(Wkr[r], Wki[r], pr, pq);
        }
    }
    // T1[r] = (w512^l)^r, w512^l = Wk[0]^2
    float T1r[8], T1i[8];
    {
        T1r[0] = 1.f; T1i[0] = 0.f;
        float br = Wkr[0], bi = Wki[0];
        cmul(br, bi, Wkr[0], Wki[0]);
        T1r[1] = br; T1i[1] = bi;
        #pragma unroll
        for (int r = 2; r < 8; ++r) {
            T1r[r] = T1r[r-1]; T1i[r] = T1i[r-1];
            cmul(T1r[r], T1i[r], br, bi);
        }
    }
    // T2[s] = (w64^(l&7))^s
    float T2r[8], T2i[8];
    {
        float s, c; sincosf(0.09817477042468103f * (float)(l & 7), &s, &c);
        T2r[0] = 1.f; T2i[0] = 0.f;
        T2r[1] = c;   T2i[1] = s;
        #pragma unroll
        for (int k = 2; k < 8; ++k) {
            T2r[k] = T2r[k-1]; T2i[k] = T2i[k-1];
            cmul(T2r[k], T2i[k], c, s);
        }
    }
    // window: lane holds z[n], n = 64w + c_, c_ = 8*(l&7) + (l>>3)
    // hann(2n) / hann(2n+1), angle = pi*w/4 + (pi/256)*c_  (+ pi/512 for odd)
    const int c_ = ((l & 7) << 3) + (l >> 3);
    float we[8], wo[8];
    {
        float sf, cf; sincosf(0.012271846303085130f * (float)c_, &sf, &cf);
        const float C2 = 0.9999811752826011f, S2 = 0.006135884649154475f;
        const float rc = 0.7071067811865476f;
        const float cw[8] = {1.f, rc, 0.f, -rc, -1.f, -rc, 0.f, rc};
        const float sw[8] = {0.f, rc, 1.f, rc, 0.f, -rc, -1.f, -rc};
        #pragma unroll
        for (int w = 0; w < 8; ++w) {
            const float ct = cw[w] * cf - sw[w] * sf;
            const float st = sw[w] * cf + cw[w] * sf;
            we[w] = 0.5f - 0.5f * ct;
            wo[w] = 0.5f - 0.5f * (ct * C2 - st * S2);
        }
    }

    __syncthreads();   // acc zero visible

    const float cs = 1.0f / 1024.0f;
    const int d = l >> 3, u = l & 7;
    const int sk1 = l + (l >> 3);        // stage-1 write base
    const int sk2 = 72 * d + u;          // stage-2 base
    const int sk3 = 9 * l;               // stage-3 base

    #pragma unroll 1
    for (int t = 0; t < 5; ++t) {
        const int fi = wv * 5 + t - 3;
        const int f  = F0 + fi;
        if (fi <= 15 && f >= 0) {
            const size_t base = ((size_t)b * FRAMES_ + f) * BINS_;

            // ---- z-prep (verified): Z[k]=E+iO at k=l+64r, scale 1/1024
            float Yr[8], Yi[8];
            #pragma unroll
            for (int r = 0; r < 8; ++r) {
                const int k = l + 64 * r;
                float ar = sre[base + k];
                float ai = sim[base + k];
                float br = sre[base + 512 - k];
                float bi = -sim[base + 512 - k];
                if (r == 0 && l == 0) { ai = 0.f; bi = 0.f; }
                const float er = (ar + br) * cs, ei = (ai + bi) * cs;
                const float dr = (ar - br) * cs, di = (ai - bi) * cs;
                const float orr = Wkr[r] * dr - Wki[r] * di;
                const float oii = Wkr[r] * di + Wki[r] * dr;
                Yr[r] = er - oii;
                Yi[r] = ei + orr;
            }

            // ---- stage 1 (registers): DFT8 over r -> m, twiddle (w512^l)^m,
            // store at a = l + 64m  (skewed: sk1 + 72m)
            dft8(Yr, Yi);
            #pragma unroll
            for (int r = 1; r < 8; ++r) cmul(Yr[r], Yi[r], T1r[r], T1i[r]);
            #pragma unroll
            for (int r = 0; r < 8; ++r) {
                Re[sk1 + 72 * r] = Yr[r];
                Im[sk1 + 72 * r] = Yi[r];
            }

            // ---- stage 2: a = 64d + u + 8v (skew sk2 + 9v), in-place,
            // DFT8 over v -> s, twiddle (w64^u)^s
            #pragma unroll
            for (int v = 0; v < 8; ++v) {
                Yr[v] = Re[sk2 + 9 * v];
                Yi[v] = Im[sk2 + 9 * v];
            }
            dft8(Yr, Yi);
            #pragma unroll
            for (int s = 1; s < 8; ++s) cmul(Yr[s], Yi[s], T2r[s], T2i[s]);
            #pragma unroll
            for (int s = 0; s < 8; ++s) {
                Re[sk2 + 9 * s] = Yr[s];
                Im[sk2 + 9 * s] = Yi[s];
            }

            // ---- stage 3: a = 8l + j (skew sk3 + j), DFT8 over j -> w
            #pragma unroll
            for (int j = 0; j < 8; ++j) {
                Yr[j] = Re[sk3 + j];
                Yi[j] = Im[sk3 + j];
            }
            dft8(Yr, Yi);
            // lane now holds z[n], n = 64w + c_  ->  x[2n]=Re, x[2n+1]=Im

            // ---- window + non-atomic accumulate (frames spaced 5: safe).
            // q is even and 8B-aligned -> float2 RMW (2 DS ops, not 4).
            const int p0 = fi * HOP_ + 2 * c_;
            #pragma unroll
            for (int w = 0; w < 8; ++w) {
                const int pos = p0 + 128 * w;
                if ((unsigned)pos < (unsigned)blen) {
                    const int q = pos + 2 * (pos >> 4);
                    float2* ap = reinterpret_cast<float2*>(&acc[q]);
                    float2 v = *ap;
                    v.x += Yr[w] * we[w];
                    v.y += Yi[w] * wo[w];
                    *ap = v;
                }
            }
        }
        __syncthreads();   // step fence (all waves, uniform)
    }

    // ---- exclusive write-out of owned span
    const size_t ob = (size_t)b * OUTLEN_ + (size_t)F0 * HOP_;
    for (int s = tid; s < blen; s += 256)
        out[ob + s] = acc[s + 2 * (s >> 4)];
}

extern "C" void kernel_launch(void* const* d_in, const int* in_sizes, int n_in,
                              void* d_out, int out_size, void* d_ws, size_t ws_size,
                              hipStream_t stream)
{
    (void)in_sizes; (void)n_in; (void)d_ws; (void)ws_size; (void)out_size;
    const float* sre = (const float*)d_in[0];
    const float* sim = (const float*)d_in[1];
    float* out = (float*)d_out;

    istft_r8_kernel<<<dim3(BPB_, BATCH_), dim3(256), 0, stream>>>(sre, sim, out);
}